// Round 5
// baseline (323.779 us; speedup 1.0000x reference)
//
#include <hip/hip_runtime.h>
#include <stdint.h>

// Problem constants
#define B_   4
#define P_   20000
#define NB_  9
#define WN_  17
#define CI_  64
#define CO_  128
#define PTS  32            // points per block -> 4 waves, each = 1 batch row x 32 points x CO=128
#define NBLK (P_ / PTS)    // 625 blocks

// Sections: s = pass*2 + kk (4 sections, each K=16 over all 17 m)
#define MCH     4          // m's per full chunk
#define NCH     5          // chunks per section: 4,4,4,4,1
#define CHBYTES 16384      // 4 m * 2 q * 128 co * 16B

typedef __fp16 f16x8 __attribute__((ext_vector_type(8)));
typedef __fp16 h2    __attribute__((ext_vector_type(2)));
typedef float  f32x16 __attribute__((ext_vector_type(16)));

union H2U { h2 h; uint32_t u; };
union F8U { f16x8 v; h2 h[4]; uint4 u; };

// async global->LDS, 16B per lane, wave-uniform LDS base (HW adds lane*16)
__device__ __forceinline__ void gload_lds16(const void* g, void* l) {
    __builtin_amdgcn_global_load_lds(
        (const __attribute__((address_space(1))) uint32_t*)g,
        (__attribute__((address_space(3))) uint32_t*)l, 16, 0, 0);
}

// wsb granule (16B = 8 f16 = 8 consecutive ci) index:
//   G = ((s*WN_ + m)*2 + q)*128 + co,  s = pass*2+kk
// source floats: weights[m][co*CI + s*16 + q*8 .. +7]
__global__ void prep_wm(const float* __restrict__ w, ushort* __restrict__ wsb) {
    int i = blockIdx.x * 256 + threadIdx.x;     // 0 .. 17407
    int co = i & 127;
    int t  = i >> 7;
    int q  = t & 1;  t >>= 1;
    int m  = t % WN_;
    int s  = t / WN_;                            // pass*2 + kk
    const float* src = w + (size_t)m * (CO_ * CI_) + co * CI_ + s * 16 + q * 8;
    float4 v0 = *(const float4*)(src);
    float4 v1 = *(const float4*)(src + 4);
    F8U h;
    h.h[0] = __builtin_amdgcn_cvt_pkrtz(v0.x, v0.y);
    h.h[1] = __builtin_amdgcn_cvt_pkrtz(v0.z, v0.w);
    h.h[2] = __builtin_amdgcn_cvt_pkrtz(v1.x, v1.y);
    h.h[3] = __builtin_amdgcn_cvt_pkrtz(v1.z, v1.w);
    *(uint4*)&wsb[(size_t)i * 8] = h.u;
}

// Round-5: occupancy push. Round 4 measured 15% occupancy = 2 waves/SIMD:
// 104 arch VGPR + 64 AGPR = 168 unified rounds past the 3-wave line (<=170,
// granule-adjusted <=160). Fix: (a) interleave stage1->mfma per m so only one
// A-fragment is live (saves ~12-16 arch regs -> ~154 unified), (b) force the
// 170-reg budget with launch_bounds(256,3) -> 3 blocks/CU, all 625 blocks in
// one co-resident round (cap 768), 12 waves/CU TLP. LDS 3x53,248=159.7KB fits.
// Spill canary: WRITE_SIZE must stay ~40 MB (round 2/3 lesson).
template <bool PRE>
__global__ __launch_bounds__(256, 3)
void lasm_fused(const float* __restrict__ in_pc,    // (B,P,CI)    f32
                const float* __restrict__ raw_w,    // (P,NB,WN)   f32
                const float* __restrict__ weights,  // (WN,CO*CI)  f32
                const float* __restrict__ bias,     // (P,CO)      f32
                const int*   __restrict__ nbr,      // (P,NB)      int32
                const ushort* __restrict__ wsb,     // pre-swizzled f16 panel
                float*       __restrict__ out)      // (B,P,CO)    f32
{
    // chunk layout: granule (mm, q, co) at byte ((mm*2+q)*128 + co)*16
    __shared__ __align__(1024) unsigned char s_buf[2 * CHBYTES];   // 32 KB double buffer
    // stride-33 pad: staging writes (bank step 9) and 32-lane reads both conflict-free
    __shared__ __align__(16) uint32_t s_w2[WN_ * NB_ * 33];        // ~20.2 KB

    const int tid  = threadIdx.x;
    const int lane = tid & 63;
    const int wv   = tid >> 6;        // batch row 0..3 (one wave per batch)
    const int arow = lane & 31;       // point-local index / A-row / co within co-tile
    const int q    = lane >> 5;       // k-half within the section's K=16
    const int p0   = blockIdx.x * PTS;

    const size_t binpc = (size_t)wv * P_ * CI_;

    h2 x[NB_][4];                      // 36 VGPRs: this section's 8 ci per lane
    auto gather = [&](int s) {         // s = pass*2 + kk
        const int ch0 = s * 16 + q * 8;
        #pragma unroll
        for (int n = 0; n < NB_; ++n) {
            uint32_t nid = (uint32_t)nbr[(size_t)(p0 + arow) * NB_ + n];
            if (nid < (uint32_t)P_) {
                const float* src = in_pc + binpc + (size_t)nid * CI_ + ch0;
                float4 a0 = *(const float4*)(src);
                float4 a1 = *(const float4*)(src + 4);
                x[n][0] = __builtin_amdgcn_cvt_pkrtz(a0.x, a0.y);
                x[n][1] = __builtin_amdgcn_cvt_pkrtz(a0.z, a0.w);
                x[n][2] = __builtin_amdgcn_cvt_pkrtz(a1.x, a1.y);
                x[n][3] = __builtin_amdgcn_cvt_pkrtz(a1.z, a1.w);
            } else {
                h2 z = {(__fp16)0.f, (__fp16)0.f};
                #pragma unroll
                for (int j = 0; j < 4; ++j) x[n][j] = z;
            }
        }
    };

    // cooperative async stage of chunk g into buf[g&1]; 1 wave-issue per wave per m
    auto issue_chunk = [&](int g) {
        if (g >= 4 * NCH) return;
        const int s    = g / NCH;
        const int cc   = g - s * NCH;
        const int m0   = cc * MCH;
        const int mcnt = (cc == NCH - 1) ? 1 : MCH;
        const uint lb  = (uint)(g & 1) * CHBYTES;
        const int gbase = (s * WN_ + m0) * 256;
        for (int i = 0; i < mcnt; ++i) {
            if (PRE) {
                const ushort* src = wsb + (size_t)(gbase + i * 256 + wv * 64 + lane) * 8;
                gload_lds16(src, s_buf + lb + (uint)(i * 4 + wv) * 1024u);
            } else {
                const int g2 = i * 256 + wv * 64 + lane;
                const int mm = g2 >> 8;
                const int qq = (g2 >> 7) & 1;
                const int co = g2 & 127;
                const float* sp = weights + (size_t)(m0 + mm) * (CO_ * CI_)
                                + co * CI_ + s * 16 + qq * 8;
                float4 v0 = *(const float4*)(sp);
                float4 v1 = *(const float4*)(sp + 4);
                F8U h;
                h.h[0] = __builtin_amdgcn_cvt_pkrtz(v0.x, v0.y);
                h.h[1] = __builtin_amdgcn_cvt_pkrtz(v0.z, v0.w);
                h.h[2] = __builtin_amdgcn_cvt_pkrtz(v1.x, v1.y);
                h.h[3] = __builtin_amdgcn_cvt_pkrtz(v1.z, v1.w);
                *(uint4*)(s_buf + lb + (uint)g2 * 16u) = h.u;
            }
        }
    };

    f32x16 acc[4];
    #pragma unroll
    for (int c = 0; c < 4; ++c)
        #pragma unroll
        for (int j = 0; j < 16; ++j) acc[c][j] = 0.f;

    // stage-1 for one m -> A-fragment (reads x + s_w2 only)
    auto stage1 = [&](int m) -> f16x8 {
        H2U wc[NB_];
        #pragma unroll
        for (int n = 0; n < NB_; ++n) wc[n].u = s_w2[(m * NB_ + n) * 33 + arow];
        F8U fa;
        #pragma unroll
        for (int r4 = 0; r4 < 4; ++r4) {
            h2 c2 = {(__fp16)0.f, (__fp16)0.f};
            #pragma unroll
            for (int n = 0; n < NB_; ++n) c2 += wc[n].h * x[n][r4];
            fa.h[r4] = c2;
        }
        return fa.v;
    };

    // B-frags from LDS (consecutive-16B per lane -> conflict-free b128) + 4 MFMAs
    auto mfma_m = [&](uint lb, int mm, f16x8 fa) {
        const uint fb = lb + (uint)(mm * 4096 + q * 2048 + arow * 16);
        F8U bf[4];
        #pragma unroll
        for (int c = 0; c < 4; ++c)
            bf[c].u = *(const uint4*)(s_buf + fb + c * 512);
        #pragma unroll
        for (int c = 0; c < 4; ++c)
            acc[c] = __builtin_amdgcn_mfma_f32_32x32x16_f16(fa, bf[c].v, acc[c], 0, 0, 0);
    };

    // ---- prologue: gathers + chunk0 fly while s_w2 stages ----
    gather(0);
    issue_chunk(0);
    for (int idx = tid; idx < PTS * NB_ * WN_; idx += 256) {
        int pl2 = idx / (NB_ * WN_);
        int rem = idx % (NB_ * WN_);
        int n   = rem / WN_;
        int m   = rem % WN_;
        float wf = raw_w[(size_t)p0 * NB_ * WN_ + idx];
        H2U c; c.h = __builtin_amdgcn_cvt_pkrtz(wf, wf);
        s_w2[(m * NB_ + n) * 33 + pl2] = c.u;
    }
    __syncthreads();

    // ---- double-buffered chunk loop (20 chunks, 1 barrier each) ----
    f16x8 ftail{};
    for (int g = 0; g < 4 * NCH; ++g) {
        issue_chunk(g + 1);                         // prefetch next chunk
        const int s  = g / NCH;
        const int cc = g - s * NCH;
        const int m0 = cc * MCH;
        const uint lb = (uint)(g & 1) * CHBYTES;
        if (cc < NCH - 1) {
            // interleaved stage1->mfma: only ONE A-fragment live at a time
            // (round-4 held f0..f3 across the chunk -> 16 extra live VGPRs)
            {
                f16x8 f0 = stage1(m0 + 0); mfma_m(lb, 0, f0);
            }
            {
                f16x8 f1 = stage1(m0 + 1); mfma_m(lb, 1, f1);
            }
            {
                f16x8 f2 = stage1(m0 + 2); mfma_m(lb, 2, f2);
            }
            {
                f16x8 f3 = stage1(m0 + 3); mfma_m(lb, 3, f3);
            }
            if (cc == NCH - 2) {
                ftail = stage1(WN_ - 1);            // tail m's stage-1 early: x dead after
                if (s < 3) gather(s + 1);           // next section's x; hides under MFMAs
            }
        } else {
            mfma_m(lb, 0, ftail);                   // B-chunk for m=16 just arrived
        }
        __syncthreads();                            // drains prefetch, guards buffer reuse
    }

    // ---- epilogue: bias + ELU + nontemporal fp32 store ----
    #pragma unroll
    for (int c = 0; c < 4; ++c) {
        int col = c * 32 + arow;
        #pragma unroll
        for (int v = 0; v < 16; ++v) {
            int lr = (v & 3) + 8 * (v >> 2) + 4 * q;   // local row 0..31 in M-tile
            int p  = p0 + lr;
            float val = acc[c][v] + bias[(size_t)p * CO_ + col];
            val = (val > 0.f) ? val : (__expf(val) - 1.f);
            __builtin_nontemporal_store(val, &out[((size_t)wv * P_ + p) * CO_ + col]);
        }
    }
}

extern "C" void kernel_launch(void* const* d_in, const int* in_sizes, int n_in,
                              void* d_out, int out_size, void* d_ws, size_t ws_size,
                              hipStream_t stream) {
    const float* in_pc   = (const float*)d_in[0];
    const float* raw_w   = (const float*)d_in[1];
    const float* weights = (const float*)d_in[2];
    const float* bias    = (const float*)d_in[3];
    const int*   nbr     = (const int*)  d_in[4];
    float* out = (float*)d_out;

    const size_t need = (size_t)4 * WN_ * 2 * 128 * 8 * sizeof(ushort);   // 278,528 B
    if (d_ws != nullptr && ws_size >= need) {
        ushort* wsb = (ushort*)d_ws;
        prep_wm<<<dim3(68), dim3(256), 0, stream>>>(weights, wsb);
        lasm_fused<true><<<dim3(NBLK), dim3(256), 0, stream>>>(
            in_pc, raw_w, weights, bias, nbr, wsb, out);
    } else {
        lasm_fused<false><<<dim3(NBLK), dim3(256), 0, stream>>>(
            in_pc, raw_w, weights, bias, nbr, nullptr, out);
    }
}

// Round 6
// 182.817 us; speedup vs baseline: 1.7711x; 1.7711x over previous
//
#include <hip/hip_runtime.h>
#include <stdint.h>

// Problem constants
#define B_   4
#define P_   20000
#define NB_  9
#define WN_  17
#define CI_  64
#define CO_  128
#define PTS  32            // points per block -> 4 waves, each = 1 batch row x 32 points x CO=128
#define NBLK (P_ / PTS)    // 625 blocks

// Sections: s = pass*2 + kk (4 sections, each K=16 over all 17 m)
#define MCH     4          // m's per full chunk
#define NCH     5          // chunks per section: 4,4,4,4,1
#define NG      (4 * NCH)  // 20 chunks total
#define CHBYTES 16384      // 4 m * 2 q * 128 co * 16B

typedef __fp16 f16x8 __attribute__((ext_vector_type(8)));
typedef __fp16 h2    __attribute__((ext_vector_type(2)));
typedef float  f32x16 __attribute__((ext_vector_type(16)));

union H2U { h2 h; uint32_t u; };
union F8U { f16x8 v; h2 h[4]; uint4 u; };

// async global->LDS, 16B per lane, wave-uniform LDS base (HW adds lane*16)
__device__ __forceinline__ void gload_lds16(const void* g, void* l) {
    __builtin_amdgcn_global_load_lds(
        (const __attribute__((address_space(1))) uint32_t*)g,
        (__attribute__((address_space(3))) uint32_t*)l, 16, 0, 0);
}

// wsb granule (16B = 8 f16 = 8 consecutive ci) index:
//   G = ((s*WN_ + m)*2 + q)*128 + co,  s = pass*2+kk
__global__ void prep_wm(const float* __restrict__ w, ushort* __restrict__ wsb) {
    int i = blockIdx.x * 256 + threadIdx.x;     // 0 .. 17407
    int co = i & 127;
    int t  = i >> 7;
    int q  = t & 1;  t >>= 1;
    int m  = t % WN_;
    int s  = t / WN_;                            // pass*2 + kk
    const float* src = w + (size_t)m * (CO_ * CI_) + co * CI_ + s * 16 + q * 8;
    float4 v0 = *(const float4*)(src);
    float4 v1 = *(const float4*)(src + 4);
    F8U h;
    h.h[0] = __builtin_amdgcn_cvt_pkrtz(v0.x, v0.y);
    h.h[1] = __builtin_amdgcn_cvt_pkrtz(v0.z, v0.w);
    h.h[2] = __builtin_amdgcn_cvt_pkrtz(v1.x, v1.y);
    h.h[3] = __builtin_amdgcn_cvt_pkrtz(v1.z, v1.w);
    *(uint4*)&wsb[(size_t)i * 8] = h.u;
}

// Round-6: (256,3) spills ~2.2KB/thread (rounds 2/5) -> stay at (256,2) and
// remove per-wave stalls instead:
//  - depth-2 prefetch, triple-buffered chunks, counted s_waitcnt vmcnt(K)
//    + raw s_barrier (T4: loads stay in flight across barriers, never drain 0)
//  - x double-buffer: next section's gather issues a full section early
//  - gather loads UNCONDITIONAL (clamped addr + cndmask zero) so per-wave
//    vmem counts are static -> K arithmetic is sound
// K(g) = c(g+2) + (g<15 ? 18 : 0), c(h) = h>=20?0 : (h%5==4?1:4)
template <bool PRE>
__global__ __launch_bounds__(256, 2)
void lasm_fused(const float* __restrict__ in_pc,    // (B,P,CI)    f32
                const float* __restrict__ raw_w,    // (P,NB,WN)   f32
                const float* __restrict__ weights,  // (WN,CO*CI)  f32
                const float* __restrict__ bias,     // (P,CO)      f32
                const int*   __restrict__ nbr,      // (P,NB)      int32
                const ushort* __restrict__ wsb,     // pre-swizzled f16 panel
                float*       __restrict__ out)      // (B,P,CO)    f32
{
    // 3 chunk buffers (depth-2 prefetch): granule (mm,q,co) at ((mm*2+q)*128+co)*16
    __shared__ __align__(1024) unsigned char s_buf[3 * CHBYTES];   // 48 KB
    // stride-33 pad: staging writes (bank step 9) and 32-lane reads conflict-free
    __shared__ __align__(16) uint32_t s_w2[WN_ * NB_ * 33];        // ~20.2 KB
    // total ~69.4 KB -> 2 blocks/CU (LDS), matching the (256,2) register limit

    const int tid  = threadIdx.x;
    const int lane = tid & 63;
    const int wv   = tid >> 6;        // batch row 0..3 (one wave per batch)
    const int arow = lane & 31;       // point-local index / A-row / co within co-tile
    const int q    = lane >> 5;       // k-half within the section's K=16
    const int p0   = blockIdx.x * PTS;

    const size_t binpc = (size_t)wv * P_ * CI_;

    // neighbor ids hoisted once (9 regs); removes 27 redundant loads and keeps
    // in-loop vmem counts static for the vmcnt arithmetic.
    uint32_t nid_r[NB_];
    #pragma unroll
    for (int n = 0; n < NB_; ++n)
        nid_r[n] = (uint32_t)nbr[(size_t)(p0 + arow) * NB_ + n];

    h2 xA[NB_][4], xB[NB_][4];        // double-buffered section inputs (36+36 regs)

    // UNCONDITIONAL gather: always 18 dwordx4 loads (clamped addr), zeroed by
    // select. Divergent-skip loads would break the static vmcnt counts.
    auto gather = [&](h2 (&x)[NB_][4], int s) {
        const int ch0 = s * 16 + q * 8;
        #pragma unroll
        for (int n = 0; n < NB_; ++n) {
            const uint32_t nid = nid_r[n];
            const uint32_t idx = (nid < (uint32_t)P_) ? nid : 0u;
            const bool     ok  = (nid < (uint32_t)P_);
            const float* src = in_pc + binpc + (size_t)idx * CI_ + ch0;
            float4 a0 = *(const float4*)(src);
            float4 a1 = *(const float4*)(src + 4);
            const h2 z = {(__fp16)0.f, (__fp16)0.f};
            x[n][0] = ok ? __builtin_amdgcn_cvt_pkrtz(a0.x, a0.y) : z;
            x[n][1] = ok ? __builtin_amdgcn_cvt_pkrtz(a0.z, a0.w) : z;
            x[n][2] = ok ? __builtin_amdgcn_cvt_pkrtz(a1.x, a1.y) : z;
            x[n][3] = ok ? __builtin_amdgcn_cvt_pkrtz(a1.z, a1.w) : z;
        }
    };

    // cooperative async stage of chunk h into buf[h%3]
    auto issue_chunk = [&](int h) {
        if (h >= NG) return;
        const int s    = h / NCH;
        const int cc   = h - s * NCH;
        const int m0   = cc * MCH;
        const int mcnt = (cc == NCH - 1) ? 1 : MCH;
        const uint lb  = (uint)(h % 3) * CHBYTES;
        const int gbase = (s * WN_ + m0) * 256;
        for (int i = 0; i < mcnt; ++i) {
            if (PRE) {
                const ushort* src = wsb + (size_t)(gbase + i * 256 + wv * 64 + lane) * 8;
                gload_lds16(src, s_buf + lb + (uint)(i * 4 + wv) * 1024u);
            } else {
                const int g2 = i * 256 + wv * 64 + lane;
                const int mm = g2 >> 8;
                const int qq = (g2 >> 7) & 1;
                const int co = g2 & 127;
                const float* sp = weights + (size_t)(m0 + mm) * (CO_ * CI_)
                                + co * CI_ + s * 16 + qq * 8;
                float4 v0 = *(const float4*)(sp);
                float4 v1 = *(const float4*)(sp + 4);
                F8U h8;
                h8.h[0] = __builtin_amdgcn_cvt_pkrtz(v0.x, v0.y);
                h8.h[1] = __builtin_amdgcn_cvt_pkrtz(v0.z, v0.w);
                h8.h[2] = __builtin_amdgcn_cvt_pkrtz(v1.x, v1.y);
                h8.h[3] = __builtin_amdgcn_cvt_pkrtz(v1.z, v1.w);
                *(uint4*)(s_buf + lb + (uint)g2 * 16u) = h8.u;
            }
        }
    };

    f32x16 acc[4];
    #pragma unroll
    for (int c = 0; c < 4; ++c)
        #pragma unroll
        for (int j = 0; j < 16; ++j) acc[c][j] = 0.f;

    auto stage1 = [&](h2 (&x)[NB_][4], int m) -> f16x8 {
        H2U wc[NB_];
        #pragma unroll
        for (int n = 0; n < NB_; ++n) wc[n].u = s_w2[(m * NB_ + n) * 33 + arow];
        F8U fa;
        #pragma unroll
        for (int r4 = 0; r4 < 4; ++r4) {
            h2 c2 = {(__fp16)0.f, (__fp16)0.f};
            #pragma unroll
            for (int n = 0; n < NB_; ++n) c2 += wc[n].h * x[n][r4];
            fa.h[r4] = c2;
        }
        return fa.v;
    };

    auto mfma_m = [&](uint lb, int mm, f16x8 fa) {
        const uint fb = lb + (uint)(mm * 4096 + q * 2048 + arow * 16);
        F8U bf[4];
        #pragma unroll
        for (int c = 0; c < 4; ++c)
            bf[c].u = *(const uint4*)(s_buf + fb + c * 512);
        #pragma unroll
        for (int c = 0; c < 4; ++c)
            acc[c] = __builtin_amdgcn_mfma_f32_32x32x16_f16(fa, bf[c].v, acc[c], 0, 0, 0);
    };

    // counted wait: K = c(g+2) + (g<15 ? 18 : 0); uniform switch keeps the
    // immediates compile-time without unrolling the whole loop.
    auto waitK = [&](int g) {
        const int h = g + 2;
        const int c = (h >= NG) ? 0 : ((h % NCH == NCH - 1) ? 1 : 4);
        const int K = c + (g < 15 ? 18 : 0);
        switch (K) {
            case 22: asm volatile("s_waitcnt vmcnt(22)" ::: "memory"); break;
            case 19: asm volatile("s_waitcnt vmcnt(19)" ::: "memory"); break;
            case 4:  asm volatile("s_waitcnt vmcnt(4)"  ::: "memory"); break;
            case 1:  asm volatile("s_waitcnt vmcnt(1)"  ::: "memory"); break;
            default: asm volatile("s_waitcnt vmcnt(0)"  ::: "memory"); break;
        }
    };

    // one section = 5 chunks; xC is this section's inputs, xN gets the next's
    auto section = [&](int s, h2 (&xC)[NB_][4], h2 (&xN)[NB_][4]) {
        for (int cc = 0; cc < NCH; ++cc) {
            const int g = s * NCH + cc;
            issue_chunk(g + 2);                       // depth-2 prefetch
            if (cc == 0 && s < 3) gather(xN, s + 1);  // ~4 chunks of latency cover
            const uint lb = (uint)(g % 3) * CHBYTES;
            if (cc < NCH - 1) {
                const int m0 = cc * MCH;
                {
                    f16x8 f0 = stage1(xC, m0 + 0); mfma_m(lb, 0, f0);
                }
                {
                    f16x8 f1 = stage1(xC, m0 + 1); mfma_m(lb, 1, f1);
                }
                {
                    f16x8 f2 = stage1(xC, m0 + 2); mfma_m(lb, 2, f2);
                }
                {
                    f16x8 f3 = stage1(xC, m0 + 3); mfma_m(lb, 3, f3);
                }
            } else {
                f16x8 ft = stage1(xC, WN_ - 1); mfma_m(lb, 0, ft);
            }
            if constexpr (PRE) {
                waitK(g);                             // chunk g+1 landed; rest in flight
                __builtin_amdgcn_s_barrier();
            } else {
                __syncthreads();                      // non-PRE path: simple drain
            }
        }
    };

    // ---- prologue: gather0 + chunks 0,1 fly while s_w2 stages; full drain ----
    gather(xA, 0);
    issue_chunk(0);
    issue_chunk(1);
    for (int idx = tid; idx < PTS * NB_ * WN_; idx += 256) {
        int pl2 = idx / (NB_ * WN_);
        int rem = idx % (NB_ * WN_);
        int n   = rem / WN_;
        int m   = rem % WN_;
        float wf = raw_w[(size_t)p0 * NB_ * WN_ + idx];
        H2U c; c.h = __builtin_amdgcn_cvt_pkrtz(wf, wf);
        s_w2[(m * NB_ + n) * 33 + pl2] = c.u;
    }
    __syncthreads();   // clean slate: chunks 0,1 + gather0 + staging all landed

    section(0, xA, xB);
    section(1, xB, xA);
    section(2, xA, xB);
    section(3, xB, xA);   // xN unused (s==3 issues no gather)

    // ---- epilogue: bias + ELU + nontemporal fp32 store ----
    #pragma unroll
    for (int c = 0; c < 4; ++c) {
        int col = c * 32 + arow;
        #pragma unroll
        for (int v = 0; v < 16; ++v) {
            int lr = (v & 3) + 8 * (v >> 2) + 4 * q;   // local row 0..31 in M-tile
            int p  = p0 + lr;
            float val = acc[c][v] + bias[(size_t)p * CO_ + col];
            val = (val > 0.f) ? val : (__expf(val) - 1.f);
            __builtin_nontemporal_store(val, &out[((size_t)wv * P_ + p) * CO_ + col]);
        }
    }
}

extern "C" void kernel_launch(void* const* d_in, const int* in_sizes, int n_in,
                              void* d_out, int out_size, void* d_ws, size_t ws_size,
                              hipStream_t stream) {
    const float* in_pc   = (const float*)d_in[0];
    const float* raw_w   = (const float*)d_in[1];
    const float* weights = (const float*)d_in[2];
    const float* bias    = (const float*)d_in[3];
    const int*   nbr     = (const int*)  d_in[4];
    float* out = (float*)d_out;

    const size_t need = (size_t)4 * WN_ * 2 * 128 * 8 * sizeof(ushort);   // 278,528 B
    if (d_ws != nullptr && ws_size >= need) {
        ushort* wsb = (ushort*)d_ws;
        prep_wm<<<dim3(68), dim3(256), 0, stream>>>(weights, wsb);
        lasm_fused<true><<<dim3(NBLK), dim3(256), 0, stream>>>(
            in_pc, raw_w, weights, bias, nbr, wsb, out);
    } else {
        lasm_fused<false><<<dim3(NBLK), dim3(256), 0, stream>>>(
            in_pc, raw_w, weights, bias, nbr, nullptr, out);
    }
}